// Round 17
// baseline (97.645 us; speedup 1.0000x reference)
//
#include <hip/hip_runtime.h>
#include <stdint.h>

// Problem constants
#define NN     64
#define CIN    64
#define TDIM   256
#define VV     25
#define KA     3
#define NT7    7
#define NTILES 4096
#define TPB    4
#define NBLKS  1024
#define ZELEMS 26214400

typedef __attribute__((ext_vector_type(8))) short bf16x8;
typedef __attribute__((ext_vector_type(8))) short short8;
typedef __attribute__((ext_vector_type(4))) float f32x4;
typedef __attribute__((ext_vector_type(4))) short short4v;

__device__ __forceinline__ short f2bf(float f) {
    uint32_t u = __builtin_bit_cast(uint32_t, f);
    u += 0x7fffu + ((u >> 16) & 1u);   // RNE
    return (short)(u >> 16);
}
__device__ __forceinline__ float bf2f(short s) {
    uint32_t u = ((uint32_t)(uint16_t)s) << 16;
    return __builtin_bit_cast(float, u);
}

// ---------------- Kernel 0: pre-convert W and A^T into bf16 fragment tables --
__global__ __launch_bounds__(256) void k_prep(
    const float* __restrict__ Wc, const float* __restrict__ A,
    unsigned short* __restrict__ Wf, unsigned short* __restrict__ Af)
{
    int idx = blockIdx.x * 256 + threadIdx.x;
    if (idx < 1536) {
        int k3 = idx / 512, r = idx & 511, ks = r >> 8, t = r & 255;
        int cl2 = t & 15, g2 = (t >> 4) & 3, wid2 = t >> 6;
        int o = k3 * 64 + wid2 * 16 + cl2;
        const float* wp = Wc + (size_t)o * CIN + ks * 32 + g2 * 8;
        float4 w0 = *(const float4*)wp;
        float4 w1 = *(const float4*)(wp + 4);
        unsigned short* d = Wf + (size_t)idx * 8;
        d[0] = f2bf(w0.x); d[1] = f2bf(w0.y); d[2] = f2bf(w0.z); d[3] = f2bf(w0.w);
        d[4] = f2bf(w1.x); d[5] = f2bf(w1.y); d[6] = f2bf(w1.z); d[7] = f2bf(w1.w);
    } else if (idx < 1536 + 384) {
        int i2 = idx - 1536;
        int k3 = i2 / 128, r = i2 & 127, ntw = r >> 6, l = r & 63;
        int cl = l & 15, g2 = l >> 4;
        int w = ntw * 16 + cl;
        unsigned short* d = Af + (size_t)i2 * 8;
#pragma unroll
        for (int j = 0; j < 8; ++j) {
            int v = g2 * 8 + j;
            float a = (v < VV && w < VV) ? A[(k3 * VV + v) * VV + w] : 0.f;
            d[j] = f2bf(a);
        }
    }
}

// stage helpers (r5-verbatim)
__device__ __forceinline__ void stage_loads(const float* __restrict__ xb, int tid,
                                            float xr[7][4]) {
#pragma unroll
    for (int j = 0; j < 7; ++j) {
        int i = tid + j * 256;
        if (i < 1600) {
            int q = i / 100, sl = i - q * 100;
            const float* p = xb + (size_t)(q * 4) * 6400 + sl;
            xr[j][0] = p[0]; xr[j][1] = p[6400];
            xr[j][2] = p[12800]; xr[j][3] = p[19200];
        }
    }
}
__device__ __forceinline__ void stage_write(short* dst, int tid, const float xr[7][4]) {
#pragma unroll
    for (int j = 0; j < 7; ++j) {
        int i = tid + j * 256;
        if (i < 1600) {
            int q = i / 100, sl = i - q * 100;
            int ks = q >> 3, lhi = (q >> 1) & 3, half = q & 1;
            int ntile = sl >> 4, lane2 = (sl & 15) | (lhi << 4);
            short4v v;
            v[0] = f2bf(xr[j][0]); v[1] = f2bf(xr[j][1]);
            v[2] = f2bf(xr[j][2]); v[3] = f2bf(xr[j][3]);
            *(short4v*)&dst[(((ntile * 2 + ks) * 64 + lane2) << 3) + half * 4] = v;
        }
    }
}

// ---------------- Kernel 1: r16 + y2 k-parity double-buffer -----------------
// Change vs r16 (69us conv, proven): y2 has TWO parity buffers; conv of k
// writes buf[k&1], adjacency of k reads buf[k&1] (k is compile-time in the
// unrolled loop). Removes the LDS WAR hazard conv(k+1)->adj(k) that
// serialized the six LDS batches per tile. Values/addresses otherwise
// identical. LDS 50.2 -> 71.7 KB (still 2 blocks/CU; occupancy is
// register-pinned anyway per r13/r14).
template<int MODE>
__global__ __launch_bounds__(256, 2) void k_conv_adj(
    const float* __restrict__ x, const float* __restrict__ bc,
    const unsigned short* __restrict__ Wf, const unsigned short* __restrict__ Af,
    float* __restrict__ zout, unsigned short* __restrict__ zbf,
    float* __restrict__ part)
{
    __shared__ __align__(16) short xbf[2][7168];   // 28.7 KB double-buffered x
    __shared__ __align__(16) short y2a[4 * 2688];  // 21.5 KB (k even)
    __shared__ __align__(16) short y2b[4 * 2688];  // 21.5 KB (k odd)

    const int tid  = threadIdx.x;
    const int lane = tid & 63;
    const int wid  = tid >> 6;
    const int cl   = lane & 15;
    const int g    = lane >> 4;

    const int tile0 = blockIdx.x * TPB;
    const int n     = tile0 >> 6;
    const int tt0   = tile0 & 63;
    const float* xslice = x + (size_t)n * CIN * TDIM * VV;

    const bf16x8* Wf8 = (const bf16x8*)Wf;
    const bf16x8* Af8 = (const bf16x8*)Af;

    bf16x8 aW[KA][2];
    float4 b4[KA];
#pragma unroll
    for (int k = 0; k < KA; ++k) {
        aW[k][0] = Wf8[(k * 2 + 0) * 256 + tid];
        aW[k][1] = Wf8[(k * 2 + 1) * 256 + tid];
        b4[k]    = *(const float4*)&bc[k * 64 + wid * 16 + g * 4];
    }

    // zero own region's v-pad columns in BOTH parity buffers (once)
    const int ybase = wid * 2688;
    for (int i = lane; i < 448; i += 64) {
        int m = i / 7, v = 25 + (i - m * 7);
        int off = ybase + m * 40 + ((m >> 4) << 3) + v;
        y2a[off] = 0;
        y2b[off] = 0;
    }

    { // stage tile 0
        float xr0[7][4];
        stage_loads(xslice + tt0 * 100, tid, xr0);
        stage_write(xbf[0], tid, xr0);
    }
    __syncthreads();

    float*          zb   = (MODE == 0) ? zout + (size_t)n * 64 * TDIM * VV : nullptr;
    unsigned short* zb16 = (MODE == 1) ? zbf  + (size_t)n * 64 * TDIM * VV : nullptr;

    int cur = 0;
    for (int it = 0; it < TPB; ++it) {
        const int tt = tt0 + it;

        float xr[7][4];
        if (it + 1 < TPB) stage_loads(xslice + (tt + 1) * 100, tid, xr);

        f32x4 zacc[4][2];
#pragma unroll
        for (int mt = 0; mt < 4; ++mt) {
            zacc[mt][0] = (f32x4){0.f, 0.f, 0.f, 0.f};
            zacc[mt][1] = (f32x4){0.f, 0.f, 0.f, 0.f};
        }

        // ---- k-loop: conv MFMA -> y2[k&1] -> adjacency MFMA ----
#pragma unroll
        for (int k = 0; k < KA; ++k) {
            short* yb = (k & 1) ? y2b : y2a;   // compile-time (k unrolled)
            bf16x8 at0 = Af8[(k * 2 + 0) * 64 + lane];
            bf16x8 at1 = Af8[(k * 2 + 1) * 64 + lane];

#pragma unroll
            for (int nt = 0; nt < NT7; ++nt) {
                bf16x8 bx0 = *(const bf16x8*)&xbf[cur][((nt * 2 + 0) * 64 + lane) << 3];
                bf16x8 bx1 = *(const bf16x8*)&xbf[cur][((nt * 2 + 1) * 64 + lane) << 3];
                f32x4 acc = {b4[k].x, b4[k].y, b4[k].z, b4[k].w};
                acc = __builtin_amdgcn_mfma_f32_16x16x32_bf16(aW[k][0], bx0, acc, 0, 0, 0);
                acc = __builtin_amdgcn_mfma_f32_16x16x32_bf16(aW[k][1], bx1, acc, 0, 0, 0);
                int s = nt * 16 + cl;
                if (s < 100) {
                    int tl = s / 25, v = s - tl * 25;
                    int base = ybase + (g * 16 + tl) * 40 + g * 8 + v;
#pragma unroll
                    for (int r = 0; r < 4; ++r)
                        yb[base + r * 160] = f2bf(acc[r]);
                }
            }
#pragma unroll
            for (int mt = 0; mt < 4; ++mt) {
                bf16x8 yf = *(const bf16x8*)&yb[ybase + (mt * 16 + cl) * 40 + mt * 8 + g * 8];
                zacc[mt][0] = __builtin_amdgcn_mfma_f32_16x16x32_bf16(yf, at0, zacc[mt][0], 0, 0, 0);
                zacc[mt][1] = __builtin_amdgcn_mfma_f32_16x16x32_bf16(yf, at1, zacc[mt][1], 0, 0, 0);
            }
        }

        if (it + 1 < TPB) stage_write(xbf[cur ^ 1], tid, xr);

        // ---- epilogue (r16-verbatim) ----
#pragma unroll
        for (int mt = 0; mt < 4; ++mt) {
            const int c = wid * 16 + mt * 4 + g;
            float s1 = 0.f, s2 = 0.f;
            if (MODE == 2) {
                short8 pz;
#pragma unroll
                for (int ntw = 0; ntw < 2; ++ntw)
#pragma unroll
                    for (int r = 0; r < 4; ++r) {
                        short b = f2bf(zacc[mt][ntw][r]);
                        pz[ntw * 4 + r] = b;
                        float val = bf2f(b);          // stats on rounded values
                        s1 += val; s2 += val * val;   // pads exact 0 -> safe
                    }
                *(short8*)&zbf[(((size_t)(tile0 + it) * 16 + wid * 4 + mt) * 64 + lane) * 8] = pz;
            } else {
#pragma unroll
                for (int ntw = 0; ntw < 2; ++ntw) {
                    int w = ntw * 16 + cl;
#pragma unroll
                    for (int r = 0; r < 4; ++r) {
                        float val = zacc[mt][ntw][r];
                        if (MODE == 1) {
                            short b = f2bf(val);
                            val = bf2f(b);
                            if (w < VV)
                                zb16[(size_t)c * 6400 + (tt * 4 + r) * VV + w] = (unsigned short)b;
                        } else {
                            if (w < VV)
                                zb[(size_t)c * 6400 + (tt * 4 + r) * VV + w] = val;
                        }
                        s1 += val; s2 += val * val;
                    }
                }
            }
            s1 += __shfl_xor(s1, 1); s2 += __shfl_xor(s2, 1);
            s1 += __shfl_xor(s1, 2); s2 += __shfl_xor(s2, 2);
            s1 += __shfl_xor(s1, 4); s2 += __shfl_xor(s2, 4);
            s1 += __shfl_xor(s1, 8); s2 += __shfl_xor(s2, 8);
            if (part != nullptr && cl == 0) {
                part[(size_t)c * NTILES + tile0 + it]          = s1;
                part[262144 + (size_t)c * NTILES + tile0 + it] = s2;
            }
        }
        __syncthreads();
        cur ^= 1;
    }
}

// ---------------- Kernel 2: reduce partials -> per-channel (a,b) -------------
__global__ __launch_bounds__(256) void k_reduce(
    const float* __restrict__ part, const float* __restrict__ gamma,
    const float* __restrict__ beta, float* __restrict__ sc)
{
    const int c = blockIdx.x;
    const float* p1 = part + (size_t)c * NTILES;
    const float* p2 = part + 262144 + (size_t)c * NTILES;
    float s1 = 0.f, s2 = 0.f;
    for (int i = threadIdx.x; i < NTILES; i += 256) { s1 += p1[i]; s2 += p2[i]; }
#pragma unroll
    for (int o = 1; o < 64; o <<= 1) { s1 += __shfl_xor(s1, o); s2 += __shfl_xor(s2, o); }
    __shared__ float r1[4], r2[4];
    if ((threadIdx.x & 63) == 0) { r1[threadIdx.x >> 6] = s1; r2[threadIdx.x >> 6] = s2; }
    __syncthreads();
    if (threadIdx.x == 0) {
        float t1 = r1[0] + r1[1] + r1[2] + r1[3];
        float t2 = r2[0] + r2[1] + r2[2] + r2[3];
        float mean = t1 * (1.f / 409600.f);
        float var  = t2 * (1.f / 409600.f) - mean * mean;
        float a = gamma[c] * rsqrtf(var + 1e-5f);
        sc[c]      = a;
        sc[64 + c] = beta[c] - mean * a;
    }
}

// ---------------- Kernel 3a: in-place fp32 normalize + ReLU -----------------
__global__ __launch_bounds__(256) void k_norm(float* __restrict__ z,
                                              const float* __restrict__ sc)
{
    __shared__ float a_s[64], b_s[64];
    if (threadIdx.x < 64) { a_s[threadIdx.x] = sc[threadIdx.x]; b_s[threadIdx.x] = sc[64 + threadIdx.x]; }
    __syncthreads();
    const int total4 = ZELEMS / 4;
    for (int i = blockIdx.x * 256 + threadIdx.x; i < total4; i += gridDim.x * 256) {
        float4 v = ((float4*)z)[i];
        int c = (i / 1600) & 63;
        float a = a_s[c], b = b_s[c];
        v.x = fmaxf(fmaf(v.x, a, b), 0.f);
        v.y = fmaxf(fmaf(v.y, a, b), 0.f);
        v.z = fmaxf(fmaf(v.z, a, b), 0.f);
        v.w = fmaxf(fmaf(v.w, a, b), 0.f);
        ((float4*)z)[i] = v;
    }
}

// ---------------- Kernel 3b: bf16 z scatter layout -> fp32 out --------------
__global__ __launch_bounds__(256) void k_norm_bf(const unsigned short* __restrict__ zbf,
                                                 float* __restrict__ out,
                                                 const float* __restrict__ sc)
{
    __shared__ float a_s[64], b_s[64];
    if (threadIdx.x < 64) { a_s[threadIdx.x] = sc[threadIdx.x]; b_s[threadIdx.x] = sc[64 + threadIdx.x]; }
    __syncthreads();
    const int total8 = ZELEMS / 8;
    for (int i = blockIdx.x * 256 + threadIdx.x; i < total8; i += gridDim.x * 256) {
        short8 v = *(const short8*)&zbf[(size_t)i * 8];
        int c = (i / 800) & 63;
        float a = a_s[c], b = b_s[c];
        float4 o0, o1;
        o0.x = fmaxf(fmaf(bf2f(v[0]), a, b), 0.f);
        o0.y = fmaxf(fmaf(bf2f(v[1]), a, b), 0.f);
        o0.z = fmaxf(fmaf(bf2f(v[2]), a, b), 0.f);
        o0.w = fmaxf(fmaf(bf2f(v[3]), a, b), 0.f);
        o1.x = fmaxf(fmaf(bf2f(v[4]), a, b), 0.f);
        o1.y = fmaxf(fmaf(bf2f(v[5]), a, b), 0.f);
        o1.z = fmaxf(fmaf(bf2f(v[6]), a, b), 0.f);
        o1.w = fmaxf(fmaf(bf2f(v[7]), a, b), 0.f);
        ((float4*)out)[(size_t)i * 2]     = o0;
        ((float4*)out)[(size_t)i * 2 + 1] = o1;
    }
}

// ---------------- Kernel 3c: packed fragment-layout z -> fp32 out -----------
// writer: (tile*1024 + (wid*4+mt)*64 + g*16+cl)*8 + ntw*4 + r
__global__ __launch_bounds__(256) void k_norm_pk(const unsigned short* __restrict__ zp,
                                                 float* __restrict__ out,
                                                 const float* __restrict__ sc)
{
    __shared__ float a_s[64], b_s[64];
    if (threadIdx.x < 64) { a_s[threadIdx.x] = sc[threadIdx.x]; b_s[threadIdx.x] = sc[64 + threadIdx.x]; }
    __syncthreads();
    const int total8 = ZELEMS / 8;
    for (int i = blockIdx.x * 256 + threadIdx.x; i < total8; i += gridDim.x * 256) {
        int e0 = i * 8;
        int nc = e0 / 6400;
        int s0 = e0 - nc * 6400;
        int n  = nc >> 6, c = nc & 63;
        int wid = c >> 4, mt = (c >> 2) & 3, g = c & 3;
        const size_t wm = (size_t)(wid * 4 + mt) * 64 + g * 16;
        float a = a_s[c], b = b_s[c];
        float o[8];
#pragma unroll
        for (int j = 0; j < 8; ++j) {
            int s = s0 + j;
            int t = s / 25;
            int w = s - t * 25;
            size_t off = ((size_t)(n * 64 + (t >> 2)) * 1024 + wm + (w & 15)) * 8
                         + (w >> 4) * 4 + (t & 3);
            o[j] = fmaxf(fmaf(bf2f((short)zp[off]), a, b), 0.f);
        }
        float4 o0 = {o[0], o[1], o[2], o[3]};
        float4 o1 = {o[4], o[5], o[6], o[7]};
        ((float4*)out)[(size_t)i * 2]     = o0;
        ((float4*)out)[(size_t)i * 2 + 1] = o1;
    }
}

extern "C" void kernel_launch(void* const* d_in, const int* in_sizes, int n_in,
                              void* d_out, int out_size, void* d_ws, size_t ws_size,
                              hipStream_t stream)
{
    const float* x     = (const float*)d_in[0];
    const float* Wc    = (const float*)d_in[1];
    const float* bc    = (const float*)d_in[2];
    const float* A     = (const float*)d_in[3];
    const float* gamma = (const float*)d_in[4];
    const float* beta  = (const float*)d_in[5];
    float* out = (float*)d_out;

    const size_t zp_b   = (size_t)NTILES * 16 * 64 * 8 * 2;   // 67.1 MB packed
    const size_t zbf_b  = (size_t)ZELEMS * 2;                 // 52.4 MB scatter
    const size_t part_b = (size_t)(2 * 64 * NTILES) * 4;      // 2 MB
    const size_t sc_b   = 512;
    const size_t wf_b   = 12288 * 2;
    const size_t af_b   = 3072 * 2;
    const size_t tail_b = part_b + sc_b + wf_b + af_b;
    const size_t need2  = zp_b  + tail_b;   // ~69.2 MB
    const size_t need1  = zbf_b + tail_b;   // ~54.5 MB
    const size_t need0  = tail_b;           // ~2.1 MB

    if (ws_size >= need2) {
        unsigned short* zp = (unsigned short*)d_ws;
        float* part = (float*)((char*)d_ws + zp_b);
        float* sc   = (float*)((char*)d_ws + zp_b + part_b);
        unsigned short* Wf = (unsigned short*)((char*)d_ws + zp_b + part_b + sc_b);
        unsigned short* Af = Wf + 12288;
        k_prep<<<8, 256, 0, stream>>>(Wc, A, Wf, Af);
        k_conv_adj<2><<<NBLKS, 256, 0, stream>>>(x, bc, Wf, Af, nullptr, zp, part);
        k_reduce<<<64, 256, 0, stream>>>(part, gamma, beta, sc);
        k_norm_pk<<<2048, 256, 0, stream>>>(zp, out, sc);
    } else if (ws_size >= need1) {
        unsigned short* zbf = (unsigned short*)d_ws;
        float* part = (float*)((char*)d_ws + zbf_b);
        float* sc   = (float*)((char*)d_ws + zbf_b + part_b);
        unsigned short* Wf = (unsigned short*)((char*)d_ws + zbf_b + part_b + sc_b);
        unsigned short* Af = Wf + 12288;
        k_prep<<<8, 256, 0, stream>>>(Wc, A, Wf, Af);
        k_conv_adj<1><<<NBLKS, 256, 0, stream>>>(x, bc, Wf, Af, nullptr, zbf, part);
        k_reduce<<<64, 256, 0, stream>>>(part, gamma, beta, sc);
        k_norm_bf<<<2048, 256, 0, stream>>>(zbf, out, sc);
    } else if (ws_size >= need0) {
        float* part = (float*)d_ws;
        float* sc   = (float*)((char*)d_ws + part_b);
        unsigned short* Wf = (unsigned short*)((char*)d_ws + part_b + sc_b);
        unsigned short* Af = Wf + 12288;
        k_prep<<<8, 256, 0, stream>>>(Wc, A, Wf, Af);
        k_conv_adj<0><<<NBLKS, 256, 0, stream>>>(x, bc, Wf, Af, out, nullptr, part);
        k_reduce<<<64, 256, 0, stream>>>(part, gamma, beta, sc);
        k_norm<<<2048, 256, 0, stream>>>(out, sc);
    }
}

// Round 18
// 85.483 us; speedup vs baseline: 1.1423x; 1.1423x over previous
//
#include <hip/hip_runtime.h>
#include <stdint.h>

// Problem constants
#define NN     64
#define CIN    64
#define TDIM   256
#define VV     25
#define KA     3
#define NT7    7
#define NTILES 4096
#define TPB    4
#define NBLKS  1024
#define ZELEMS 26214400

typedef __attribute__((ext_vector_type(8))) short bf16x8;
typedef __attribute__((ext_vector_type(8))) short short8;
typedef __attribute__((ext_vector_type(4))) float f32x4;
typedef __attribute__((ext_vector_type(4))) short short4v;

__device__ __forceinline__ short f2bf(float f) {
    uint32_t u = __builtin_bit_cast(uint32_t, f);
    u += 0x7fffu + ((u >> 16) & 1u);   // RNE
    return (short)(u >> 16);
}
__device__ __forceinline__ float bf2f(short s) {
    uint32_t u = ((uint32_t)(uint16_t)s) << 16;
    return __builtin_bit_cast(float, u);
}

// ---------------- Kernel 0: pre-convert W and A^T into bf16 fragment tables --
__global__ __launch_bounds__(256) void k_prep(
    const float* __restrict__ Wc, const float* __restrict__ A,
    unsigned short* __restrict__ Wf, unsigned short* __restrict__ Af)
{
    int idx = blockIdx.x * 256 + threadIdx.x;
    if (idx < 1536) {
        int k3 = idx / 512, r = idx & 511, ks = r >> 8, t = r & 255;
        int cl2 = t & 15, g2 = (t >> 4) & 3, wid2 = t >> 6;
        int o = k3 * 64 + wid2 * 16 + cl2;
        const float* wp = Wc + (size_t)o * CIN + ks * 32 + g2 * 8;
        float4 w0 = *(const float4*)wp;
        float4 w1 = *(const float4*)(wp + 4);
        unsigned short* d = Wf + (size_t)idx * 8;
        d[0] = f2bf(w0.x); d[1] = f2bf(w0.y); d[2] = f2bf(w0.z); d[3] = f2bf(w0.w);
        d[4] = f2bf(w1.x); d[5] = f2bf(w1.y); d[6] = f2bf(w1.z); d[7] = f2bf(w1.w);
    } else if (idx < 1536 + 384) {
        int i2 = idx - 1536;
        int k3 = i2 / 128, r = i2 & 127, ntw = r >> 6, l = r & 63;
        int cl = l & 15, g2 = l >> 4;
        int w = ntw * 16 + cl;
        unsigned short* d = Af + (size_t)i2 * 8;
#pragma unroll
        for (int j = 0; j < 8; ++j) {
            int v = g2 * 8 + j;
            float a = (v < VV && w < VV) ? A[(k3 * VV + v) * VV + w] : 0.f;
            d[j] = f2bf(a);
        }
    }
}

// stage helpers (r5-verbatim)
__device__ __forceinline__ void stage_loads(const float* __restrict__ xb, int tid,
                                            float xr[7][4]) {
#pragma unroll
    for (int j = 0; j < 7; ++j) {
        int i = tid + j * 256;
        if (i < 1600) {
            int q = i / 100, sl = i - q * 100;
            const float* p = xb + (size_t)(q * 4) * 6400 + sl;
            xr[j][0] = p[0]; xr[j][1] = p[6400];
            xr[j][2] = p[12800]; xr[j][3] = p[19200];
        }
    }
}
__device__ __forceinline__ void stage_write(short* dst, int tid, const float xr[7][4]) {
#pragma unroll
    for (int j = 0; j < 7; ++j) {
        int i = tid + j * 256;
        if (i < 1600) {
            int q = i / 100, sl = i - q * 100;
            int ks = q >> 3, lhi = (q >> 1) & 3, half = q & 1;
            int ntile = sl >> 4, lane2 = (sl & 15) | (lhi << 4);
            short4v v;
            v[0] = f2bf(xr[j][0]); v[1] = f2bf(xr[j][1]);
            v[2] = f2bf(xr[j][2]); v[3] = f2bf(xr[j][3]);
            *(short4v*)&dst[(((ntile * 2 + ks) * 64 + lane2) << 3) + half * 4] = v;
        }
    }
}

// ---------------- Kernel 1: r17 + manual k-stagger + deferred stats ---------
// Source order conv0->a, conv1->b, adj0(a), conv2->a, adj1(b), adj2(a):
// each adj(k)'s LDS write->read RAW bubble is covered by the following
// conv/adj phase's issued instructions (in-order wave issue). Values
// identical to r16/r17. Stats accumulated in regs across the 4 tiles;
// one shuffle-reduce + store per block (was per tile).
template<int MODE>
__global__ __launch_bounds__(256, 2) void k_conv_adj(
    const float* __restrict__ x, const float* __restrict__ bc,
    const unsigned short* __restrict__ Wf, const unsigned short* __restrict__ Af,
    float* __restrict__ zout, unsigned short* __restrict__ zbf,
    float* __restrict__ part)
{
    __shared__ __align__(16) short xbf[2][7168];   // 28.7 KB double-buffered x
    __shared__ __align__(16) short y2a[4 * 2688];  // 21.5 KB parity A
    __shared__ __align__(16) short y2b[4 * 2688];  // 21.5 KB parity B

    const int tid  = threadIdx.x;
    const int lane = tid & 63;
    const int wid  = tid >> 6;
    const int cl   = lane & 15;
    const int g    = lane >> 4;

    const int tile0 = blockIdx.x * TPB;
    const int n     = tile0 >> 6;
    const int tt0   = tile0 & 63;
    const float* xslice = x + (size_t)n * CIN * TDIM * VV;

    const bf16x8* Wf8 = (const bf16x8*)Wf;
    const bf16x8* Af8 = (const bf16x8*)Af;

    bf16x8 aW[KA][2], at[KA][2];
    float4 b4[KA];
#pragma unroll
    for (int k = 0; k < KA; ++k) {
        aW[k][0] = Wf8[(k * 2 + 0) * 256 + tid];
        aW[k][1] = Wf8[(k * 2 + 1) * 256 + tid];
        at[k][0] = Af8[(k * 2 + 0) * 64 + lane];
        at[k][1] = Af8[(k * 2 + 1) * 64 + lane];
        b4[k]    = *(const float4*)&bc[k * 64 + wid * 16 + g * 4];
    }

    // zero own region's v-pad columns in BOTH parity buffers (once)
    const int ybase = wid * 2688;
    for (int i = lane; i < 448; i += 64) {
        int m = i / 7, v = 25 + (i - m * 7);
        int off = ybase + m * 40 + ((m >> 4) << 3) + v;
        y2a[off] = 0;
        y2b[off] = 0;
    }

    { // stage tile 0
        float xr0[7][4];
        stage_loads(xslice + tt0 * 100, tid, xr0);
        stage_write(xbf[0], tid, xr0);
    }
    __syncthreads();

    float*          zb   = (MODE == 0) ? zout + (size_t)n * 64 * TDIM * VV : nullptr;
    unsigned short* zb16 = (MODE == 1) ? zbf  + (size_t)n * 64 * TDIM * VV : nullptr;

    float s1acc[4] = {0.f, 0.f, 0.f, 0.f};
    float s2acc[4] = {0.f, 0.f, 0.f, 0.f};

// conv phase for compile-time K into buffer YB (values r16-identical)
#define CONV_PHASE(K, YB)                                                        \
    {                                                                            \
        _Pragma("unroll")                                                        \
        for (int nt = 0; nt < NT7; ++nt) {                                       \
            bf16x8 bx0 = *(const bf16x8*)&xbf[cur][((nt * 2 + 0) * 64 + lane) << 3]; \
            bf16x8 bx1 = *(const bf16x8*)&xbf[cur][((nt * 2 + 1) * 64 + lane) << 3]; \
            f32x4 acc = {b4[K].x, b4[K].y, b4[K].z, b4[K].w};                    \
            acc = __builtin_amdgcn_mfma_f32_16x16x32_bf16(aW[K][0], bx0, acc, 0, 0, 0); \
            acc = __builtin_amdgcn_mfma_f32_16x16x32_bf16(aW[K][1], bx1, acc, 0, 0, 0); \
            int s = nt * 16 + cl;                                                \
            if (s < 100) {                                                       \
                int tl = s / 25, v = s - tl * 25;                                \
                int base = ybase + (g * 16 + tl) * 40 + g * 8 + v;               \
                _Pragma("unroll")                                                \
                for (int r = 0; r < 4; ++r)                                      \
                    (YB)[base + r * 160] = f2bf(acc[r]);                         \
            }                                                                    \
        }                                                                        \
    }

#define ADJ_PHASE(K, YB)                                                         \
    {                                                                            \
        _Pragma("unroll")                                                        \
        for (int mt = 0; mt < 4; ++mt) {                                         \
            bf16x8 yf = *(const bf16x8*)&(YB)[ybase + (mt * 16 + cl) * 40 + mt * 8 + g * 8]; \
            zacc[mt][0] = __builtin_amdgcn_mfma_f32_16x16x32_bf16(yf, at[K][0], zacc[mt][0], 0, 0, 0); \
            zacc[mt][1] = __builtin_amdgcn_mfma_f32_16x16x32_bf16(yf, at[K][1], zacc[mt][1], 0, 0, 0); \
        }                                                                        \
    }

    int cur = 0;
    for (int it = 0; it < TPB; ++it) {
        const int tt = tt0 + it;

        float xr[7][4];
        if (it + 1 < TPB) stage_loads(xslice + (tt + 1) * 100, tid, xr);

        f32x4 zacc[4][2];
#pragma unroll
        for (int mt = 0; mt < 4; ++mt) {
            zacc[mt][0] = (f32x4){0.f, 0.f, 0.f, 0.f};
            zacc[mt][1] = (f32x4){0.f, 0.f, 0.f, 0.f};
        }

        // ---- staggered k-schedule: RAW bubbles covered by next phase ----
        CONV_PHASE(0, y2a)
        CONV_PHASE(1, y2b)
        ADJ_PHASE(0, y2a)
        CONV_PHASE(2, y2a)   // overwrites a AFTER adj0's reads (in-order, safe)
        ADJ_PHASE(1, y2b)
        ADJ_PHASE(2, y2a)

        if (it + 1 < TPB) stage_write(xbf[cur ^ 1], tid, xr);

        // ---- epilogue: z store + per-tile stats into register accumulators --
#pragma unroll
        for (int mt = 0; mt < 4; ++mt) {
            const int c = wid * 16 + mt * 4 + g;
            float s1 = 0.f, s2 = 0.f;
            if (MODE == 2) {
                short8 pz;
#pragma unroll
                for (int ntw = 0; ntw < 2; ++ntw)
#pragma unroll
                    for (int r = 0; r < 4; ++r) {
                        short b = f2bf(zacc[mt][ntw][r]);
                        pz[ntw * 4 + r] = b;
                        float val = bf2f(b);          // stats on rounded values
                        s1 += val; s2 += val * val;   // pads exact 0 -> safe
                    }
                *(short8*)&zbf[(((size_t)(tile0 + it) * 16 + wid * 4 + mt) * 64 + lane) * 8] = pz;
            } else {
#pragma unroll
                for (int ntw = 0; ntw < 2; ++ntw) {
                    int w = ntw * 16 + cl;
#pragma unroll
                    for (int r = 0; r < 4; ++r) {
                        float val = zacc[mt][ntw][r];
                        if (MODE == 1) {
                            short b = f2bf(val);
                            val = bf2f(b);
                            if (w < VV)
                                zb16[(size_t)c * 6400 + (tt * 4 + r) * VV + w] = (unsigned short)b;
                        } else {
                            if (w < VV)
                                zb[(size_t)c * 6400 + (tt * 4 + r) * VV + w] = val;
                        }
                        s1 += val; s2 += val * val;
                    }
                }
            }
            s1acc[mt] += s1;
            s2acc[mt] += s2;
        }
        __syncthreads();
        cur ^= 1;
    }

    // ---- once per block: shuffle-reduce the 4-tile stats and store ----
    if (part != nullptr) {
#pragma unroll
        for (int mt = 0; mt < 4; ++mt) {
            float s1 = s1acc[mt], s2 = s2acc[mt];
            s1 += __shfl_xor(s1, 1); s2 += __shfl_xor(s2, 1);
            s1 += __shfl_xor(s1, 2); s2 += __shfl_xor(s2, 2);
            s1 += __shfl_xor(s1, 4); s2 += __shfl_xor(s2, 4);
            s1 += __shfl_xor(s1, 8); s2 += __shfl_xor(s2, 8);
            if (cl == 0) {
                const int c = wid * 16 + mt * 4 + g;
                part[(size_t)c * NBLKS + blockIdx.x]         = s1;
                part[65536 + (size_t)c * NBLKS + blockIdx.x] = s2;
            }
        }
    }
#undef CONV_PHASE
#undef ADJ_PHASE
}

// ---------------- Kernel 2: reduce partials -> per-channel (a,b) -------------
__global__ __launch_bounds__(256) void k_reduce(
    const float* __restrict__ part, const float* __restrict__ gamma,
    const float* __restrict__ beta, float* __restrict__ sc)
{
    const int c = blockIdx.x;
    const float* p1 = part + (size_t)c * NBLKS;
    const float* p2 = part + 65536 + (size_t)c * NBLKS;
    float s1 = 0.f, s2 = 0.f;
    for (int i = threadIdx.x; i < NBLKS; i += 256) { s1 += p1[i]; s2 += p2[i]; }
#pragma unroll
    for (int o = 1; o < 64; o <<= 1) { s1 += __shfl_xor(s1, o); s2 += __shfl_xor(s2, o); }
    __shared__ float r1[4], r2[4];
    if ((threadIdx.x & 63) == 0) { r1[threadIdx.x >> 6] = s1; r2[threadIdx.x >> 6] = s2; }
    __syncthreads();
    if (threadIdx.x == 0) {
        float t1 = r1[0] + r1[1] + r1[2] + r1[3];
        float t2 = r2[0] + r2[1] + r2[2] + r2[3];
        float mean = t1 * (1.f / 409600.f);
        float var  = t2 * (1.f / 409600.f) - mean * mean;
        float a = gamma[c] * rsqrtf(var + 1e-5f);
        sc[c]      = a;
        sc[64 + c] = beta[c] - mean * a;
    }
}

// ---------------- Kernel 3a: in-place fp32 normalize + ReLU -----------------
__global__ __launch_bounds__(256) void k_norm(float* __restrict__ z,
                                              const float* __restrict__ sc)
{
    __shared__ float a_s[64], b_s[64];
    if (threadIdx.x < 64) { a_s[threadIdx.x] = sc[threadIdx.x]; b_s[threadIdx.x] = sc[64 + threadIdx.x]; }
    __syncthreads();
    const int total4 = ZELEMS / 4;
    for (int i = blockIdx.x * 256 + threadIdx.x; i < total4; i += gridDim.x * 256) {
        float4 v = ((float4*)z)[i];
        int c = (i / 1600) & 63;
        float a = a_s[c], b = b_s[c];
        v.x = fmaxf(fmaf(v.x, a, b), 0.f);
        v.y = fmaxf(fmaf(v.y, a, b), 0.f);
        v.z = fmaxf(fmaf(v.z, a, b), 0.f);
        v.w = fmaxf(fmaf(v.w, a, b), 0.f);
        ((float4*)z)[i] = v;
    }
}

// ---------------- Kernel 3b: bf16 z scatter layout -> fp32 out --------------
__global__ __launch_bounds__(256) void k_norm_bf(const unsigned short* __restrict__ zbf,
                                                 float* __restrict__ out,
                                                 const float* __restrict__ sc)
{
    __shared__ float a_s[64], b_s[64];
    if (threadIdx.x < 64) { a_s[threadIdx.x] = sc[threadIdx.x]; b_s[threadIdx.x] = sc[64 + threadIdx.x]; }
    __syncthreads();
    const int total8 = ZELEMS / 8;
    for (int i = blockIdx.x * 256 + threadIdx.x; i < total8; i += gridDim.x * 256) {
        short8 v = *(const short8*)&zbf[(size_t)i * 8];
        int c = (i / 800) & 63;
        float a = a_s[c], b = b_s[c];
        float4 o0, o1;
        o0.x = fmaxf(fmaf(bf2f(v[0]), a, b), 0.f);
        o0.y = fmaxf(fmaf(bf2f(v[1]), a, b), 0.f);
        o0.z = fmaxf(fmaf(bf2f(v[2]), a, b), 0.f);
        o0.w = fmaxf(fmaf(bf2f(v[3]), a, b), 0.f);
        o1.x = fmaxf(fmaf(bf2f(v[4]), a, b), 0.f);
        o1.y = fmaxf(fmaf(bf2f(v[5]), a, b), 0.f);
        o1.z = fmaxf(fmaf(bf2f(v[6]), a, b), 0.f);
        o1.w = fmaxf(fmaf(bf2f(v[7]), a, b), 0.f);
        ((float4*)out)[(size_t)i * 2]     = o0;
        ((float4*)out)[(size_t)i * 2 + 1] = o1;
    }
}

// ---------------- Kernel 3c: packed fragment-layout z -> fp32 out -----------
// writer: (tile*1024 + (wid*4+mt)*64 + g*16+cl)*8 + ntw*4 + r
__global__ __launch_bounds__(256) void k_norm_pk(const unsigned short* __restrict__ zp,
                                                 float* __restrict__ out,
                                                 const float* __restrict__ sc)
{
    __shared__ float a_s[64], b_s[64];
    if (threadIdx.x < 64) { a_s[threadIdx.x] = sc[threadIdx.x]; b_s[threadIdx.x] = sc[64 + threadIdx.x]; }
    __syncthreads();
    const int total8 = ZELEMS / 8;
    for (int i = blockIdx.x * 256 + threadIdx.x; i < total8; i += gridDim.x * 256) {
        int e0 = i * 8;
        int nc = e0 / 6400;
        int s0 = e0 - nc * 6400;
        int n  = nc >> 6, c = nc & 63;
        int wid = c >> 4, mt = (c >> 2) & 3, g = c & 3;
        const size_t wm = (size_t)(wid * 4 + mt) * 64 + g * 16;
        float a = a_s[c], b = b_s[c];
        float o[8];
#pragma unroll
        for (int j = 0; j < 8; ++j) {
            int s = s0 + j;
            int t = s / 25;
            int w = s - t * 25;
            size_t off = ((size_t)(n * 64 + (t >> 2)) * 1024 + wm + (w & 15)) * 8
                         + (w >> 4) * 4 + (t & 3);
            o[j] = fmaxf(fmaf(bf2f((short)zp[off]), a, b), 0.f);
        }
        float4 o0 = {o[0], o[1], o[2], o[3]};
        float4 o1 = {o[4], o[5], o[6], o[7]};
        ((float4*)out)[(size_t)i * 2]     = o0;
        ((float4*)out)[(size_t)i * 2 + 1] = o1;
    }
}

extern "C" void kernel_launch(void* const* d_in, const int* in_sizes, int n_in,
                              void* d_out, int out_size, void* d_ws, size_t ws_size,
                              hipStream_t stream)
{
    const float* x     = (const float*)d_in[0];
    const float* Wc    = (const float*)d_in[1];
    const float* bc    = (const float*)d_in[2];
    const float* A     = (const float*)d_in[3];
    const float* gamma = (const float*)d_in[4];
    const float* beta  = (const float*)d_in[5];
    float* out = (float*)d_out;

    const size_t zp_b   = (size_t)NTILES * 16 * 64 * 8 * 2;   // 67.1 MB packed
    const size_t zbf_b  = (size_t)ZELEMS * 2;                 // 52.4 MB scatter
    const size_t part_b = (size_t)(2 * 64 * NBLKS) * 4;       // 512 KB
    const size_t sc_b   = 512;
    const size_t wf_b   = 12288 * 2;
    const size_t af_b   = 3072 * 2;
    const size_t tail_b = part_b + sc_b + wf_b + af_b;
    const size_t need2  = zp_b  + tail_b;
    const size_t need1  = zbf_b + tail_b;
    const size_t need0  = tail_b;

    if (ws_size >= need2) {
        unsigned short* zp = (unsigned short*)d_ws;
        float* part = (float*)((char*)d_ws + zp_b);
        float* sc   = (float*)((char*)d_ws + zp_b + part_b);
        unsigned short* Wf = (unsigned short*)((char*)d_ws + zp_b + part_b + sc_b);
        unsigned short* Af = Wf + 12288;
        k_prep<<<8, 256, 0, stream>>>(Wc, A, Wf, Af);
        k_conv_adj<2><<<NBLKS, 256, 0, stream>>>(x, bc, Wf, Af, nullptr, zp, part);
        k_reduce<<<64, 256, 0, stream>>>(part, gamma, beta, sc);
        k_norm_pk<<<2048, 256, 0, stream>>>(zp, out, sc);
    } else if (ws_size >= need1) {
        unsigned short* zbf = (unsigned short*)d_ws;
        float* part = (float*)((char*)d_ws + zbf_b);
        float* sc   = (float*)((char*)d_ws + zbf_b + part_b);
        unsigned short* Wf = (unsigned short*)((char*)d_ws + zbf_b + part_b + sc_b);
        unsigned short* Af = Wf + 12288;
        k_prep<<<8, 256, 0, stream>>>(Wc, A, Wf, Af);
        k_conv_adj<1><<<NBLKS, 256, 0, stream>>>(x, bc, Wf, Af, nullptr, zbf, part);
        k_reduce<<<64, 256, 0, stream>>>(part, gamma, beta, sc);
        k_norm_bf<<<2048, 256, 0, stream>>>(zbf, out, sc);
    } else if (ws_size >= need0) {
        float* part = (float*)d_ws;
        float* sc   = (float*)((char*)d_ws + part_b);
        unsigned short* Wf = (unsigned short*)((char*)d_ws + part_b + sc_b);
        unsigned short* Af = Wf + 12288;
        k_prep<<<8, 256, 0, stream>>>(Wc, A, Wf, Af);
        k_conv_adj<0><<<NBLKS, 256, 0, stream>>>(x, bc, Wf, Af, out, nullptr, part);
        k_reduce<<<64, 256, 0, stream>>>(part, gamma, beta, sc);
        k_norm<<<2048, 256, 0, stream>>>(out, sc);
    }
}

// Round 19
// 83.818 us; speedup vs baseline: 1.1650x; 1.0199x over previous
//
#include <hip/hip_runtime.h>
#include <stdint.h>

// Problem constants
#define NN     64
#define CIN    64
#define TDIM   256
#define VV     25
#define KA     3
#define NT7    7
#define NTILES 4096
#define TPB    4
#define NBLKS  1024
#define ZELEMS 26214400

typedef __attribute__((ext_vector_type(8))) short bf16x8;
typedef __attribute__((ext_vector_type(8))) short short8;
typedef __attribute__((ext_vector_type(4))) float f32x4;
typedef __attribute__((ext_vector_type(4))) short short4v;

__device__ __forceinline__ short f2bf(float f) {
    uint32_t u = __builtin_bit_cast(uint32_t, f);
    u += 0x7fffu + ((u >> 16) & 1u);   // RNE
    return (short)(u >> 16);
}
__device__ __forceinline__ float bf2f(short s) {
    uint32_t u = ((uint32_t)(uint16_t)s) << 16;
    return __builtin_bit_cast(float, u);
}

// ---------------- Kernel 0: pre-convert W and A^T into bf16 fragment tables --
__global__ __launch_bounds__(256) void k_prep(
    const float* __restrict__ Wc, const float* __restrict__ A,
    unsigned short* __restrict__ Wf, unsigned short* __restrict__ Af)
{
    int idx = blockIdx.x * 256 + threadIdx.x;
    if (idx < 1536) {
        int k3 = idx / 512, r = idx & 511, ks = r >> 8, t = r & 255;
        int cl2 = t & 15, g2 = (t >> 4) & 3, wid2 = t >> 6;
        int o = k3 * 64 + wid2 * 16 + cl2;
        const float* wp = Wc + (size_t)o * CIN + ks * 32 + g2 * 8;
        float4 w0 = *(const float4*)wp;
        float4 w1 = *(const float4*)(wp + 4);
        unsigned short* d = Wf + (size_t)idx * 8;
        d[0] = f2bf(w0.x); d[1] = f2bf(w0.y); d[2] = f2bf(w0.z); d[3] = f2bf(w0.w);
        d[4] = f2bf(w1.x); d[5] = f2bf(w1.y); d[6] = f2bf(w1.z); d[7] = f2bf(w1.w);
    } else if (idx < 1536 + 384) {
        int i2 = idx - 1536;
        int k3 = i2 / 128, r = i2 & 127, ntw = r >> 6, l = r & 63;
        int cl = l & 15, g2 = l >> 4;
        int w = ntw * 16 + cl;
        unsigned short* d = Af + (size_t)i2 * 8;
#pragma unroll
        for (int j = 0; j < 8; ++j) {
            int v = g2 * 8 + j;
            float a = (v < VV && w < VV) ? A[(k3 * VV + v) * VV + w] : 0.f;
            d[j] = f2bf(a);
        }
    }
}

// stage helpers (r5-verbatim)
__device__ __forceinline__ void stage_loads(const float* __restrict__ xb, int tid,
                                            float xr[7][4]) {
#pragma unroll
    for (int j = 0; j < 7; ++j) {
        int i = tid + j * 256;
        if (i < 1600) {
            int q = i / 100, sl = i - q * 100;
            const float* p = xb + (size_t)(q * 4) * 6400 + sl;
            xr[j][0] = p[0]; xr[j][1] = p[6400];
            xr[j][2] = p[12800]; xr[j][3] = p[19200];
        }
    }
}
__device__ __forceinline__ void stage_write(short* dst, int tid, const float xr[7][4]) {
#pragma unroll
    for (int j = 0; j < 7; ++j) {
        int i = tid + j * 256;
        if (i < 1600) {
            int q = i / 100, sl = i - q * 100;
            int ks = q >> 3, lhi = (q >> 1) & 3, half = q & 1;
            int ntile = sl >> 4, lane2 = (sl & 15) | (lhi << 4);
            short4v v;
            v[0] = f2bf(xr[j][0]); v[1] = f2bf(xr[j][1]);
            v[2] = f2bf(xr[j][2]); v[3] = f2bf(xr[j][3]);
            *(short4v*)&dst[(((ntile * 2 + ks) * 64 + lane2) << 3) + half * 4] = v;
        }
    }
}

// ---------------- Kernel 1: r18 + bx register hoist (LDS-op diet) -----------
// vs r18 (64us conv, proven): conv B-frags bx[7][2] read from LDS ONCE per
// tile (r13-proven pattern) instead of re-read in every CONV_PHASE: 42 -> 14
// ds_read_b128 per tile per wave (-20% LDS-pipe pressure, the busiest pipe).
// Stagger schedule, parity buffers, deferred stats all r18-verbatim.
template<int MODE>
__global__ __launch_bounds__(256, 2) void k_conv_adj(
    const float* __restrict__ x, const float* __restrict__ bc,
    const unsigned short* __restrict__ Wf, const unsigned short* __restrict__ Af,
    float* __restrict__ zout, unsigned short* __restrict__ zbf,
    float* __restrict__ part)
{
    __shared__ __align__(16) short xbf[2][7168];   // 28.7 KB double-buffered x
    __shared__ __align__(16) short y2a[4 * 2688];  // 21.5 KB parity A
    __shared__ __align__(16) short y2b[4 * 2688];  // 21.5 KB parity B

    const int tid  = threadIdx.x;
    const int lane = tid & 63;
    const int wid  = tid >> 6;
    const int cl   = lane & 15;
    const int g    = lane >> 4;

    const int tile0 = blockIdx.x * TPB;
    const int n     = tile0 >> 6;
    const int tt0   = tile0 & 63;
    const float* xslice = x + (size_t)n * CIN * TDIM * VV;

    const bf16x8* Wf8 = (const bf16x8*)Wf;
    const bf16x8* Af8 = (const bf16x8*)Af;

    bf16x8 aW[KA][2], at[KA][2];
    float4 b4[KA];
#pragma unroll
    for (int k = 0; k < KA; ++k) {
        aW[k][0] = Wf8[(k * 2 + 0) * 256 + tid];
        aW[k][1] = Wf8[(k * 2 + 1) * 256 + tid];
        at[k][0] = Af8[(k * 2 + 0) * 64 + lane];
        at[k][1] = Af8[(k * 2 + 1) * 64 + lane];
        b4[k]    = *(const float4*)&bc[k * 64 + wid * 16 + g * 4];
    }

    // zero own region's v-pad columns in BOTH parity buffers (once)
    const int ybase = wid * 2688;
    for (int i = lane; i < 448; i += 64) {
        int m = i / 7, v = 25 + (i - m * 7);
        int off = ybase + m * 40 + ((m >> 4) << 3) + v;
        y2a[off] = 0;
        y2b[off] = 0;
    }

    { // stage tile 0
        float xr0[7][4];
        stage_loads(xslice + tt0 * 100, tid, xr0);
        stage_write(xbf[0], tid, xr0);
    }
    __syncthreads();

    float*          zb   = (MODE == 0) ? zout + (size_t)n * 64 * TDIM * VV : nullptr;
    unsigned short* zb16 = (MODE == 1) ? zbf  + (size_t)n * 64 * TDIM * VV : nullptr;

    float s1acc[4] = {0.f, 0.f, 0.f, 0.f};
    float s2acc[4] = {0.f, 0.f, 0.f, 0.f};

// conv phase for compile-time K into buffer YB (bx from registers)
#define CONV_PHASE(K, YB)                                                        \
    {                                                                            \
        _Pragma("unroll")                                                        \
        for (int nt = 0; nt < NT7; ++nt) {                                       \
            f32x4 acc = {b4[K].x, b4[K].y, b4[K].z, b4[K].w};                    \
            acc = __builtin_amdgcn_mfma_f32_16x16x32_bf16(aW[K][0], bx[nt][0], acc, 0, 0, 0); \
            acc = __builtin_amdgcn_mfma_f32_16x16x32_bf16(aW[K][1], bx[nt][1], acc, 0, 0, 0); \
            int s = nt * 16 + cl;                                                \
            if (s < 100) {                                                       \
                int tl = s / 25, v = s - tl * 25;                                \
                int base = ybase + (g * 16 + tl) * 40 + g * 8 + v;               \
                _Pragma("unroll")                                                \
                for (int r = 0; r < 4; ++r)                                      \
                    (YB)[base + r * 160] = f2bf(acc[r]);                         \
            }                                                                    \
        }                                                                        \
    }

#define ADJ_PHASE(K, YB)                                                         \
    {                                                                            \
        _Pragma("unroll")                                                        \
        for (int mt = 0; mt < 4; ++mt) {                                         \
            bf16x8 yf = *(const bf16x8*)&(YB)[ybase + (mt * 16 + cl) * 40 + mt * 8 + g * 8]; \
            zacc[mt][0] = __builtin_amdgcn_mfma_f32_16x16x32_bf16(yf, at[K][0], zacc[mt][0], 0, 0, 0); \
            zacc[mt][1] = __builtin_amdgcn_mfma_f32_16x16x32_bf16(yf, at[K][1], zacc[mt][1], 0, 0, 0); \
        }                                                                        \
    }

    int cur = 0;
    for (int it = 0; it < TPB; ++it) {
        const int tt = tt0 + it;

        float xr[7][4];
        if (it + 1 < TPB) stage_loads(xslice + (tt + 1) * 100, tid, xr);

        // preload conv B-frags ONCE per tile (r13-proven; -28 LDS reads/tile)
        bf16x8 bx[NT7][2];
#pragma unroll
        for (int nt = 0; nt < NT7; ++nt) {
            bx[nt][0] = *(const bf16x8*)&xbf[cur][((nt * 2 + 0) * 64 + lane) << 3];
            bx[nt][1] = *(const bf16x8*)&xbf[cur][((nt * 2 + 1) * 64 + lane) << 3];
        }

        f32x4 zacc[4][2];
#pragma unroll
        for (int mt = 0; mt < 4; ++mt) {
            zacc[mt][0] = (f32x4){0.f, 0.f, 0.f, 0.f};
            zacc[mt][1] = (f32x4){0.f, 0.f, 0.f, 0.f};
        }

        // ---- staggered k-schedule (r18-verbatim) ----
        CONV_PHASE(0, y2a)
        CONV_PHASE(1, y2b)
        ADJ_PHASE(0, y2a)
        CONV_PHASE(2, y2a)   // overwrites a AFTER adj0's reads (in-order, safe)
        ADJ_PHASE(1, y2b)
        ADJ_PHASE(2, y2a)

        if (it + 1 < TPB) stage_write(xbf[cur ^ 1], tid, xr);

        // ---- epilogue: z store + per-tile stats into register accumulators --
#pragma unroll
        for (int mt = 0; mt < 4; ++mt) {
            const int c = wid * 16 + mt * 4 + g;
            float s1 = 0.f, s2 = 0.f;
            if (MODE == 2) {
                short8 pz;
#pragma unroll
                for (int ntw = 0; ntw < 2; ++ntw)
#pragma unroll
                    for (int r = 0; r < 4; ++r) {
                        short b = f2bf(zacc[mt][ntw][r]);
                        pz[ntw * 4 + r] = b;
                        float val = bf2f(b);          // stats on rounded values
                        s1 += val; s2 += val * val;   // pads exact 0 -> safe
                    }
                *(short8*)&zbf[(((size_t)(tile0 + it) * 16 + wid * 4 + mt) * 64 + lane) * 8] = pz;
            } else {
#pragma unroll
                for (int ntw = 0; ntw < 2; ++ntw) {
                    int w = ntw * 16 + cl;
#pragma unroll
                    for (int r = 0; r < 4; ++r) {
                        float val = zacc[mt][ntw][r];
                        if (MODE == 1) {
                            short b = f2bf(val);
                            val = bf2f(b);
                            if (w < VV)
                                zb16[(size_t)c * 6400 + (tt * 4 + r) * VV + w] = (unsigned short)b;
                        } else {
                            if (w < VV)
                                zb[(size_t)c * 6400 + (tt * 4 + r) * VV + w] = val;
                        }
                        s1 += val; s2 += val * val;
                    }
                }
            }
            s1acc[mt] += s1;
            s2acc[mt] += s2;
        }
        __syncthreads();
        cur ^= 1;
    }

    // ---- once per block: shuffle-reduce the 4-tile stats and store ----
    if (part != nullptr) {
#pragma unroll
        for (int mt = 0; mt < 4; ++mt) {
            float s1 = s1acc[mt], s2 = s2acc[mt];
            s1 += __shfl_xor(s1, 1); s2 += __shfl_xor(s2, 1);
            s1 += __shfl_xor(s1, 2); s2 += __shfl_xor(s2, 2);
            s1 += __shfl_xor(s1, 4); s2 += __shfl_xor(s2, 4);
            s1 += __shfl_xor(s1, 8); s2 += __shfl_xor(s2, 8);
            if (cl == 0) {
                const int c = wid * 16 + mt * 4 + g;
                part[(size_t)c * NBLKS + blockIdx.x]         = s1;
                part[65536 + (size_t)c * NBLKS + blockIdx.x] = s2;
            }
        }
    }
#undef CONV_PHASE
#undef ADJ_PHASE
}

// ---------------- Kernel 2: reduce partials -> per-channel (a,b) -------------
__global__ __launch_bounds__(256) void k_reduce(
    const float* __restrict__ part, const float* __restrict__ gamma,
    const float* __restrict__ beta, float* __restrict__ sc)
{
    const int c = blockIdx.x;
    const float* p1 = part + (size_t)c * NBLKS;
    const float* p2 = part + 65536 + (size_t)c * NBLKS;
    float s1 = 0.f, s2 = 0.f;
    for (int i = threadIdx.x; i < NBLKS; i += 256) { s1 += p1[i]; s2 += p2[i]; }
#pragma unroll
    for (int o = 1; o < 64; o <<= 1) { s1 += __shfl_xor(s1, o); s2 += __shfl_xor(s2, o); }
    __shared__ float r1[4], r2[4];
    if ((threadIdx.x & 63) == 0) { r1[threadIdx.x >> 6] = s1; r2[threadIdx.x >> 6] = s2; }
    __syncthreads();
    if (threadIdx.x == 0) {
        float t1 = r1[0] + r1[1] + r1[2] + r1[3];
        float t2 = r2[0] + r2[1] + r2[2] + r2[3];
        float mean = t1 * (1.f / 409600.f);
        float var  = t2 * (1.f / 409600.f) - mean * mean;
        float a = gamma[c] * rsqrtf(var + 1e-5f);
        sc[c]      = a;
        sc[64 + c] = beta[c] - mean * a;
    }
}

// ---------------- Kernel 3a: in-place fp32 normalize + ReLU -----------------
__global__ __launch_bounds__(256) void k_norm(float* __restrict__ z,
                                              const float* __restrict__ sc)
{
    __shared__ float a_s[64], b_s[64];
    if (threadIdx.x < 64) { a_s[threadIdx.x] = sc[threadIdx.x]; b_s[threadIdx.x] = sc[64 + threadIdx.x]; }
    __syncthreads();
    const int total4 = ZELEMS / 4;
    for (int i = blockIdx.x * 256 + threadIdx.x; i < total4; i += gridDim.x * 256) {
        float4 v = ((float4*)z)[i];
        int c = (i / 1600) & 63;
        float a = a_s[c], b = b_s[c];
        v.x = fmaxf(fmaf(v.x, a, b), 0.f);
        v.y = fmaxf(fmaf(v.y, a, b), 0.f);
        v.z = fmaxf(fmaf(v.z, a, b), 0.f);
        v.w = fmaxf(fmaf(v.w, a, b), 0.f);
        ((float4*)z)[i] = v;
    }
}

// ---------------- Kernel 3b: bf16 z scatter layout -> fp32 out --------------
__global__ __launch_bounds__(256) void k_norm_bf(const unsigned short* __restrict__ zbf,
                                                 float* __restrict__ out,
                                                 const float* __restrict__ sc)
{
    __shared__ float a_s[64], b_s[64];
    if (threadIdx.x < 64) { a_s[threadIdx.x] = sc[threadIdx.x]; b_s[threadIdx.x] = sc[64 + threadIdx.x]; }
    __syncthreads();
    const int total8 = ZELEMS / 8;
    for (int i = blockIdx.x * 256 + threadIdx.x; i < total8; i += gridDim.x * 256) {
        short8 v = *(const short8*)&zbf[(size_t)i * 8];
        int c = (i / 800) & 63;
        float a = a_s[c], b = b_s[c];
        float4 o0, o1;
        o0.x = fmaxf(fmaf(bf2f(v[0]), a, b), 0.f);
        o0.y = fmaxf(fmaf(bf2f(v[1]), a, b), 0.f);
        o0.z = fmaxf(fmaf(bf2f(v[2]), a, b), 0.f);
        o0.w = fmaxf(fmaf(bf2f(v[3]), a, b), 0.f);
        o1.x = fmaxf(fmaf(bf2f(v[4]), a, b), 0.f);
        o1.y = fmaxf(fmaf(bf2f(v[5]), a, b), 0.f);
        o1.z = fmaxf(fmaf(bf2f(v[6]), a, b), 0.f);
        o1.w = fmaxf(fmaf(bf2f(v[7]), a, b), 0.f);
        ((float4*)out)[(size_t)i * 2]     = o0;
        ((float4*)out)[(size_t)i * 2 + 1] = o1;
    }
}

// ---------------- Kernel 3c: packed fragment-layout z -> fp32 out -----------
// writer: (tile*1024 + (wid*4+mt)*64 + g*16+cl)*8 + ntw*4 + r
__global__ __launch_bounds__(256) void k_norm_pk(const unsigned short* __restrict__ zp,
                                                 float* __restrict__ out,
                                                 const float* __restrict__ sc)
{
    __shared__ float a_s[64], b_s[64];
    if (threadIdx.x < 64) { a_s[threadIdx.x] = sc[threadIdx.x]; b_s[threadIdx.x] = sc[64 + threadIdx.x]; }
    __syncthreads();
    const int total8 = ZELEMS / 8;
    for (int i = blockIdx.x * 256 + threadIdx.x; i < total8; i += gridDim.x * 256) {
        int e0 = i * 8;
        int nc = e0 / 6400;
        int s0 = e0 - nc * 6400;
        int n  = nc >> 6, c = nc & 63;
        int wid = c >> 4, mt = (c >> 2) & 3, g = c & 3;
        const size_t wm = (size_t)(wid * 4 + mt) * 64 + g * 16;
        float a = a_s[c], b = b_s[c];
        float o[8];
#pragma unroll
        for (int j = 0; j < 8; ++j) {
            int s = s0 + j;
            int t = s / 25;
            int w = s - t * 25;
            size_t off = ((size_t)(n * 64 + (t >> 2)) * 1024 + wm + (w & 15)) * 8
                         + (w >> 4) * 4 + (t & 3);
            o[j] = fmaxf(fmaf(bf2f((short)zp[off]), a, b), 0.f);
        }
        float4 o0 = {o[0], o[1], o[2], o[3]};
        float4 o1 = {o[4], o[5], o[6], o[7]};
        ((float4*)out)[(size_t)i * 2]     = o0;
        ((float4*)out)[(size_t)i * 2 + 1] = o1;
    }
}

extern "C" void kernel_launch(void* const* d_in, const int* in_sizes, int n_in,
                              void* d_out, int out_size, void* d_ws, size_t ws_size,
                              hipStream_t stream)
{
    const float* x     = (const float*)d_in[0];
    const float* Wc    = (const float*)d_in[1];
    const float* bc    = (const float*)d_in[2];
    const float* A     = (const float*)d_in[3];
    const float* gamma = (const float*)d_in[4];
    const float* beta  = (const float*)d_in[5];
    float* out = (float*)d_out;

    const size_t zp_b   = (size_t)NTILES * 16 * 64 * 8 * 2;   // 67.1 MB packed
    const size_t zbf_b  = (size_t)ZELEMS * 2;                 // 52.4 MB scatter
    const size_t part_b = (size_t)(2 * 64 * NBLKS) * 4;       // 512 KB
    const size_t sc_b   = 512;
    const size_t wf_b   = 12288 * 2;
    const size_t af_b   = 3072 * 2;
    const size_t tail_b = part_b + sc_b + wf_b + af_b;
    const size_t need2  = zp_b  + tail_b;
    const size_t need1  = zbf_b + tail_b;
    const size_t need0  = tail_b;

    if (ws_size >= need2) {
        unsigned short* zp = (unsigned short*)d_ws;
        float* part = (float*)((char*)d_ws + zp_b);
        float* sc   = (float*)((char*)d_ws + zp_b + part_b);
        unsigned short* Wf = (unsigned short*)((char*)d_ws + zp_b + part_b + sc_b);
        unsigned short* Af = Wf + 12288;
        k_prep<<<8, 256, 0, stream>>>(Wc, A, Wf, Af);
        k_conv_adj<2><<<NBLKS, 256, 0, stream>>>(x, bc, Wf, Af, nullptr, zp, part);
        k_reduce<<<64, 256, 0, stream>>>(part, gamma, beta, sc);
        k_norm_pk<<<2048, 256, 0, stream>>>(zp, out, sc);
    } else if (ws_size >= need1) {
        unsigned short* zbf = (unsigned short*)d_ws;
        float* part = (float*)((char*)d_ws + zbf_b);
        float* sc   = (float*)((char*)d_ws + zbf_b + part_b);
        unsigned short* Wf = (unsigned short*)((char*)d_ws + zbf_b + part_b + sc_b);
        unsigned short* Af = Wf + 12288;
        k_prep<<<8, 256, 0, stream>>>(Wc, A, Wf, Af);
        k_conv_adj<1><<<NBLKS, 256, 0, stream>>>(x, bc, Wf, Af, nullptr, zbf, part);
        k_reduce<<<64, 256, 0, stream>>>(part, gamma, beta, sc);
        k_norm_bf<<<2048, 256, 0, stream>>>(zbf, out, sc);
    } else if (ws_size >= need0) {
        float* part = (float*)d_ws;
        float* sc   = (float*)((char*)d_ws + part_b);
        unsigned short* Wf = (unsigned short*)((char*)d_ws + part_b + sc_b);
        unsigned short* Af = Wf + 12288;
        k_prep<<<8, 256, 0, stream>>>(Wc, A, Wf, Af);
        k_conv_adj<0><<<NBLKS, 256, 0, stream>>>(x, bc, Wf, Af, out, nullptr, part);
        k_reduce<<<64, 256, 0, stream>>>(part, gamma, beta, sc);
        k_norm<<<2048, 256, 0, stream>>>(out, sc);
    }
}